// Round 1
// baseline (301.440 us; speedup 1.0000x reference)
//
#include <hip/hip_runtime.h>
#include <math.h>

#define B 8
#define T 8192
#define D 512
#define M 512
#define POS 32
#define KIN (D + POS)          // 544
#define CHUNK 16
#define NCHUNK (T / CHUNK)     // 512
#define BM (B * M)             // 4096

// ---------------- K1: per-chunk sums ----------------
// grid = B*NCHUNK blocks, 128 threads, thread handles 4 consecutive d (float4)
// writes cp[b, c+1, :] = sum of 16 rows; block c==0 also zeroes cp[b, 0, :]
__global__ __launch_bounds__(128) void k_chunksum(const float* __restrict__ fe,
                                                  float* __restrict__ cp) {
    int blk = blockIdx.x;
    int b = blk / NCHUNK;
    int c = blk % NCHUNK;
    int d4 = threadIdx.x << 2;
    const float* src = fe + ((size_t)(b * T + c * CHUNK) * D + d4);
    float4 acc = {0.f, 0.f, 0.f, 0.f};
#pragma unroll
    for (int r = 0; r < CHUNK; ++r) {
        float4 v = *(const float4*)(src + (size_t)r * D);
        acc.x += v.x; acc.y += v.y; acc.z += v.z; acc.w += v.w;
    }
    float* dst = cp + ((size_t)b * (NCHUNK + 1) + (c + 1)) * D + d4;
    *(float4*)dst = acc;
    if (c == 0) {
        float4 z = {0.f, 0.f, 0.f, 0.f};
        *(float4*)(cp + (size_t)b * (NCHUNK + 1) * D + d4) = z;
    }
}

// ---------------- K2: in-place exclusive scan over chunks ----------------
// grid = B*(D/64) blocks of 64 threads; each thread owns one (b,d) column.
// After: cp[b,c,:] = sum of chunks [0,c)  (cp[b,0,:]=0 from K1)
__global__ __launch_bounds__(64) void k_scan(float* __restrict__ cp) {
    int b = blockIdx.x / (D / 64);
    int d = (blockIdx.x % (D / 64)) * 64 + threadIdx.x;
    float* base = cp + (size_t)b * (NCHUNK + 1) * D + d;
    float acc = 0.f;
#pragma unroll 4
    for (int c = 1; c <= NCHUNK; ++c) {
        acc += base[(size_t)c * D];
        base[(size_t)c * D] = acc;
    }
}

// ---------------- K3: segment means + fourier -> X[4096, 544] ----------------
// grid = BM blocks, 128 threads (float4 over d)
__global__ __launch_bounds__(128) void k_buildx(const float* __restrict__ fe,
                                                const int* __restrict__ bounds,
                                                const float* __restrict__ cp,
                                                float* __restrict__ X) {
    int bm = blockIdx.x;
    int b = bm / M;
    int m = bm % M;
    int b0 = bounds[bm * 2 + 0];
    int b1 = bounds[bm * 2 + 1];
    int s = min(max(b0, 0), T - 1);
    int e = max(min(b1, T), s + 1);
    int cs_ = s / CHUNK, ce = e / CHUNK;
    int d4 = threadIdx.x << 2;

    const float* cpb = cp + (size_t)b * (NCHUNK + 1) * D;
    float4 pe = *(const float4*)(cpb + (size_t)ce * D + d4);
    float4 ps = *(const float4*)(cpb + (size_t)cs_ * D + d4);
    float4 acc;
    acc.x = pe.x - ps.x; acc.y = pe.y - ps.y;
    acc.z = pe.z - ps.z; acc.w = pe.w - ps.w;

    const float* feb = fe + (size_t)b * T * D + d4;
    for (int t = ce * CHUNK; t < e; ++t) {
        float4 v = *(const float4*)(feb + (size_t)t * D);
        acc.x += v.x; acc.y += v.y; acc.z += v.z; acc.w += v.w;
    }
    for (int t = cs_ * CHUNK; t < s; ++t) {
        float4 v = *(const float4*)(feb + (size_t)t * D);
        acc.x -= v.x; acc.y -= v.y; acc.z -= v.z; acc.w -= v.w;
    }
    float inv = 1.0f / (float)(e - s);
    acc.x *= inv; acc.y *= inv; acc.z *= inv; acc.w *= inv;

    float* xr = X + (size_t)bm * KIN;
    *(float4*)(xr + d4) = acc;

    int t = threadIdx.x;
    if (t < POS) {
        int i = t & 15;
        float freq = expf(0.46051701859880914f * (float)i);  // 1000^(i/15)
        float pos = (float)m * (1.0f / 511.0f);
        float ang = pos * freq;
        xr[D + t] = (t < 16) ? sinf(ang) : cosf(ang);
    }
}

// ---------------- K4: Out[4096,512] = X[4096,544] @ W[544,512] + b ----------
// fp32 vector GEMM, 64x64 tile, 256 threads, 4x4 microkernel
#define TM 64
#define TN 64
#define TKc 16
__global__ __launch_bounds__(256) void k_gemm(const float* __restrict__ X,
                                              const float* __restrict__ W,
                                              const float* __restrict__ bias,
                                              float* __restrict__ out) {
    __shared__ float Xs[TKc][TM + 4];  // row stride 68 floats (272B, 16B-aligned)
    __shared__ float Ws[TKc][TN + 4];
    int n0 = blockIdx.x * TN;
    int m0 = blockIdx.y * TM;
    int tid = threadIdx.x;
    int tx = tid & 15, ty = tid >> 4;

    float acc[4][4] = {{0.f}};

    for (int k0 = 0; k0 < KIN; k0 += TKc) {
        // stage X tile (64 rows x 16 k), transposed into Xs[k][m]
        {
            int mrow = tid >> 2;
            int kq = (tid & 3) << 2;
            float4 v = *(const float4*)(X + (size_t)(m0 + mrow) * KIN + k0 + kq);
            Xs[kq + 0][mrow] = v.x;
            Xs[kq + 1][mrow] = v.y;
            Xs[kq + 2][mrow] = v.z;
            Xs[kq + 3][mrow] = v.w;
            int krow = tid >> 4;
            int nq = (tid & 15) << 2;
            float4 w = *(const float4*)(W + (size_t)(k0 + krow) * D + n0 + nq);
            *(float4*)&Ws[krow][nq] = w;
        }
        __syncthreads();
#pragma unroll
        for (int k = 0; k < TKc; ++k) {
            float4 a = *(const float4*)&Xs[k][ty << 2];
            float4 w = *(const float4*)&Ws[k][tx << 2];
            acc[0][0] += a.x * w.x; acc[0][1] += a.x * w.y; acc[0][2] += a.x * w.z; acc[0][3] += a.x * w.w;
            acc[1][0] += a.y * w.x; acc[1][1] += a.y * w.y; acc[1][2] += a.y * w.z; acc[1][3] += a.y * w.w;
            acc[2][0] += a.z * w.x; acc[2][1] += a.z * w.y; acc[2][2] += a.z * w.z; acc[2][3] += a.z * w.w;
            acc[3][0] += a.w * w.x; acc[3][1] += a.w * w.y; acc[3][2] += a.w * w.z; acc[3][3] += a.w * w.w;
        }
        __syncthreads();
    }

    float4 bv = *(const float4*)(bias + n0 + (tx << 2));
#pragma unroll
    for (int i = 0; i < 4; ++i) {
        float4 o;
        o.x = acc[i][0] + bv.x;
        o.y = acc[i][1] + bv.y;
        o.z = acc[i][2] + bv.z;
        o.w = acc[i][3] + bv.w;
        *(float4*)(out + (size_t)(m0 + (ty << 2) + i) * D + n0 + (tx << 2)) = o;
    }
}

extern "C" void kernel_launch(void* const* d_in, const int* in_sizes, int n_in,
                              void* d_out, int out_size, void* d_ws, size_t ws_size,
                              hipStream_t stream) {
    const float* fe = (const float*)d_in[0];
    const int* bounds = (const int*)d_in[1];
    const float* W = (const float*)d_in[2];
    const float* bias = (const float*)d_in[3];
    float* out = (float*)d_out;

    float* cp = (float*)d_ws;                               // B*(NCHUNK+1)*D floats = 8.4 MB
    float* X = cp + (size_t)B * (NCHUNK + 1) * D;           // BM*KIN floats = 8.9 MB

    k_chunksum<<<B * NCHUNK, 128, 0, stream>>>(fe, cp);
    k_scan<<<B * (D / 64), 64, 0, stream>>>(cp);
    k_buildx<<<BM, 128, 0, stream>>>(fe, bounds, cp, X);
    dim3 g(D / TN, BM / TM);
    k_gemm<<<g, 256, 0, stream>>>(X, W, bias, out);
}

// Round 2
// 282.199 us; speedup vs baseline: 1.0682x; 1.0682x over previous
//
#include <hip/hip_runtime.h>
#include <math.h>

#define B 8
#define T 8192
#define D 512
#define M 512
#define POS 32
#define KIN (D + POS)          // 544
#define CHUNK 16
#define NCHUNK (T / CHUNK)     // 512 fine chunks per batch
#define GRP 16                 // fine chunks per coarse group
#define NGRP (NCHUNK / GRP)    // 32 coarse groups per batch
#define BM (B * M)             // 4096

// ---------------- K1: fine chunk sums ----------------
// cp[b, c, d] = sum of frame_emb rows [c*16, c*16+16)
__global__ __launch_bounds__(128) void k_chunksum(const float* __restrict__ fe,
                                                  float* __restrict__ cp) {
    int blk = blockIdx.x;
    int b = blk / NCHUNK;
    int c = blk % NCHUNK;
    int d4 = threadIdx.x << 2;
    const float* src = fe + ((size_t)(b * T + c * CHUNK) * D + d4);
    float4 acc = {0.f, 0.f, 0.f, 0.f};
#pragma unroll
    for (int r = 0; r < CHUNK; ++r) {
        float4 v = *(const float4*)(src + (size_t)r * D);
        acc.x += v.x; acc.y += v.y; acc.z += v.z; acc.w += v.w;
    }
    *(float4*)(cp + ((size_t)b * NCHUNK + c) * D + d4) = acc;
}

// ---------------- K2a: in-place inclusive scan within each coarse group ------
// after: cp[b,c,:] = sum of fine chunks [g*16 .. c] where g = c>>4
// also writes gsum[b,g,:] = coarse group total
__global__ __launch_bounds__(128) void k_scan_fine(float* __restrict__ cp,
                                                   float* __restrict__ gsum) {
    int b = blockIdx.x / NGRP;
    int g = blockIdx.x % NGRP;
    int d4 = threadIdx.x << 2;
    float* base = cp + ((size_t)b * NCHUNK + (size_t)g * GRP) * D + d4;
    float4 acc = {0.f, 0.f, 0.f, 0.f};
#pragma unroll
    for (int k = 0; k < GRP; ++k) {
        float4 v = *(const float4*)(base + (size_t)k * D);
        acc.x += v.x; acc.y += v.y; acc.z += v.z; acc.w += v.w;
        *(float4*)(base + (size_t)k * D) = acc;
    }
    *(float4*)(gsum + ((size_t)b * NGRP + g) * D + d4) = acc;
}

// ---------------- K2b: exclusive scan of the 32 coarse totals per batch ------
// gx[b, g, :] for g in [0,32]; gx[b,32,:] = grand total
__global__ __launch_bounds__(128) void k_scan_coarse(const float* __restrict__ gsum,
                                                     float* __restrict__ gx) {
    int b = blockIdx.x;
    int d4 = threadIdx.x << 2;
    float4 acc = {0.f, 0.f, 0.f, 0.f};
#pragma unroll
    for (int g = 0; g < NGRP; ++g) {
        *(float4*)(gx + ((size_t)b * (NGRP + 1) + g) * D + d4) = acc;
        float4 v = *(const float4*)(gsum + ((size_t)b * NGRP + g) * D + d4);
        acc.x += v.x; acc.y += v.y; acc.z += v.z; acc.w += v.w;
    }
    *(float4*)(gx + ((size_t)b * (NGRP + 1) + NGRP) * D + d4) = acc;
}

// ---------------- K3: segment means + fourier -> X[4096, 544] ----------------
// chunk-prefix(c) = gx[b, c>>4] + (c&15 ? cp[b, c-1] : 0)
__global__ __launch_bounds__(128) void k_buildx(const float* __restrict__ fe,
                                                const int* __restrict__ bounds,
                                                const float* __restrict__ cp,
                                                const float* __restrict__ gx,
                                                float* __restrict__ X) {
    int bm = blockIdx.x;
    int b = bm / M;
    int m = bm % M;
    int b0 = bounds[bm * 2 + 0];
    int b1 = bounds[bm * 2 + 1];
    int s = min(max(b0, 0), T - 1);
    int e = max(min(b1, T), s + 1);
    int cs_ = s >> 4, ce = e >> 4;
    int d4 = threadIdx.x << 2;

    const float* cpb = cp + (size_t)b * NCHUNK * D;
    const float* gxb = gx + (size_t)b * (NGRP + 1) * D;

    // prefix(ce)
    float4 acc = *(const float4*)(gxb + (size_t)(ce >> 4) * D + d4);
    if (ce & 15) {
        float4 v = *(const float4*)(cpb + (size_t)(ce - 1) * D + d4);
        acc.x += v.x; acc.y += v.y; acc.z += v.z; acc.w += v.w;
    }
    // minus prefix(cs)
    {
        float4 p = *(const float4*)(gxb + (size_t)(cs_ >> 4) * D + d4);
        acc.x -= p.x; acc.y -= p.y; acc.z -= p.z; acc.w -= p.w;
        if (cs_ & 15) {
            float4 v = *(const float4*)(cpb + (size_t)(cs_ - 1) * D + d4);
            acc.x -= v.x; acc.y -= v.y; acc.z -= v.z; acc.w -= v.w;
        }
    }

    const float* feb = fe + (size_t)b * T * D + d4;
    for (int t = ce * CHUNK; t < e; ++t) {
        float4 v = *(const float4*)(feb + (size_t)t * D);
        acc.x += v.x; acc.y += v.y; acc.z += v.z; acc.w += v.w;
    }
    for (int t = cs_ * CHUNK; t < s; ++t) {
        float4 v = *(const float4*)(feb + (size_t)t * D);
        acc.x -= v.x; acc.y -= v.y; acc.z -= v.z; acc.w -= v.w;
    }
    float inv = 1.0f / (float)(e - s);
    acc.x *= inv; acc.y *= inv; acc.z *= inv; acc.w *= inv;

    float* xr = X + (size_t)bm * KIN;
    *(float4*)(xr + d4) = acc;

    int t = threadIdx.x;
    if (t < POS) {
        int i = t & 15;
        float freq = expf(0.46051701859880914f * (float)i);  // 1000^(i/15)
        float pos = (float)m * (1.0f / 511.0f);
        float ang = pos * freq;
        xr[D + t] = (t < 16) ? sinf(ang) : cosf(ang);
    }
}

// ---------------- K4: Out[4096,512] = X[4096,544] @ W[544,512] + b ----------
// fp32 vector GEMM, 128x64 tile, 256 threads, 8x4 microkernel (32 FMA : 3 b128)
#define TM 128
#define TN 64
#define TKc 16
__global__ __launch_bounds__(256) void k_gemm(const float* __restrict__ X,
                                              const float* __restrict__ W,
                                              const float* __restrict__ bias,
                                              float* __restrict__ out) {
    __shared__ float Xs[TKc][TM + 4];  // k-row stride 132 floats
    __shared__ float Ws[TKc][TN + 4];
    int n0 = blockIdx.x * TN;
    int m0 = blockIdx.y * TM;
    int tid = threadIdx.x;
    int tx = tid & 15, ty = tid >> 4;

    float acc[8][4] = {{0.f}};

    for (int k0 = 0; k0 < KIN; k0 += TKc) {  // 34 iterations
        // stage X tile: 128 rows x 16 k, transposed. thread -> row=tid>>1, 8 k's
        {
            int row = tid >> 1;
            int kq = (tid & 1) << 3;
            const float* xp = X + (size_t)(m0 + row) * KIN + k0 + kq;
            float4 v0 = *(const float4*)xp;
            float4 v1 = *(const float4*)(xp + 4);
            Xs[kq + 0][row] = v0.x; Xs[kq + 1][row] = v0.y;
            Xs[kq + 2][row] = v0.z; Xs[kq + 3][row] = v0.w;
            Xs[kq + 4][row] = v1.x; Xs[kq + 5][row] = v1.y;
            Xs[kq + 6][row] = v1.z; Xs[kq + 7][row] = v1.w;
            // stage W tile: 16 rows x 64 cols
            float4 w = *(const float4*)(W + (size_t)(k0 + ty) * D + n0 + (tx << 2));
            *(float4*)&Ws[ty][tx << 2] = w;
        }
        __syncthreads();
#pragma unroll
        for (int k = 0; k < TKc; ++k) {
            float4 a0 = *(const float4*)&Xs[k][ty << 3];
            float4 a1 = *(const float4*)&Xs[k][(ty << 3) + 4];
            float4 w4 = *(const float4*)&Ws[k][tx << 2];
            acc[0][0] += a0.x * w4.x; acc[0][1] += a0.x * w4.y; acc[0][2] += a0.x * w4.z; acc[0][3] += a0.x * w4.w;
            acc[1][0] += a0.y * w4.x; acc[1][1] += a0.y * w4.y; acc[1][2] += a0.y * w4.z; acc[1][3] += a0.y * w4.w;
            acc[2][0] += a0.z * w4.x; acc[2][1] += a0.z * w4.y; acc[2][2] += a0.z * w4.z; acc[2][3] += a0.z * w4.w;
            acc[3][0] += a0.w * w4.x; acc[3][1] += a0.w * w4.y; acc[3][2] += a0.w * w4.z; acc[3][3] += a0.w * w4.w;
            acc[4][0] += a1.x * w4.x; acc[4][1] += a1.x * w4.y; acc[4][2] += a1.x * w4.z; acc[4][3] += a1.x * w4.w;
            acc[5][0] += a1.y * w4.x; acc[5][1] += a1.y * w4.y; acc[5][2] += a1.y * w4.z; acc[5][3] += a1.y * w4.w;
            acc[6][0] += a1.z * w4.x; acc[6][1] += a1.z * w4.y; acc[6][2] += a1.z * w4.z; acc[6][3] += a1.z * w4.w;
            acc[7][0] += a1.w * w4.x; acc[7][1] += a1.w * w4.y; acc[7][2] += a1.w * w4.z; acc[7][3] += a1.w * w4.w;
        }
        __syncthreads();
    }

    float4 bv = *(const float4*)(bias + n0 + (tx << 2));
#pragma unroll
    for (int i = 0; i < 8; ++i) {
        float4 o;
        o.x = acc[i][0] + bv.x;
        o.y = acc[i][1] + bv.y;
        o.z = acc[i][2] + bv.z;
        o.w = acc[i][3] + bv.w;
        *(float4*)(out + (size_t)(m0 + (ty << 3) + i) * D + n0 + (tx << 2)) = o;
    }
}

extern "C" void kernel_launch(void* const* d_in, const int* in_sizes, int n_in,
                              void* d_out, int out_size, void* d_ws, size_t ws_size,
                              hipStream_t stream) {
    const float* fe = (const float*)d_in[0];
    const int* bounds = (const int*)d_in[1];
    const float* W = (const float*)d_in[2];
    const float* bias = (const float*)d_in[3];
    float* out = (float*)d_out;

    float* cp = (float*)d_ws;                                  // B*NCHUNK*D = 8 MB
    float* gsum = cp + (size_t)B * NCHUNK * D;                 // B*32*D = 512 KB
    float* gx = gsum + (size_t)B * NGRP * D;                   // B*33*D = 528 KB
    float* X = gx + (size_t)B * (NGRP + 1) * D;                // BM*KIN = 8.5 MB

    k_chunksum<<<B * NCHUNK, 128, 0, stream>>>(fe, cp);
    k_scan_fine<<<B * NGRP, 128, 0, stream>>>(cp, gsum);
    k_scan_coarse<<<B, 128, 0, stream>>>(gsum, gx);
    k_buildx<<<BM, 128, 0, stream>>>(fe, bounds, cp, gx, X);
    dim3 g(D / TN, BM / TM);
    k_gemm<<<g, 256, 0, stream>>>(X, W, bias, out);
}

// Round 3
// 267.883 us; speedup vs baseline: 1.1253x; 1.0534x over previous
//
#include <hip/hip_runtime.h>
#include <math.h>

#define B 8
#define T 8192
#define D 512
#define M 512
#define POS 32
#define KIN (D + POS)          // 544
#define CHUNK 16
#define NCHUNK (T / CHUNK)     // 512 fine chunks per batch
#define GRP 16                 // fine chunks per coarse group
#define NGRP (NCHUNK / GRP)    // 32 coarse groups per batch
#define BM (B * M)             // 4096

// ---------------- K1: fused chunk-sum + intra-group inclusive scan ----------
// grid = B*NGRP*2 blocks (b, g, half-of-D), 64 threads (1 wave, float4 each).
// cp[b, g*16+c, :] = inclusive prefix (within group g) of 16-row chunk sums.
// gsum[b, g, :] = group total.
__global__ __launch_bounds__(64) void k_scanchunk(const float* __restrict__ fe,
                                                  float* __restrict__ cp,
                                                  float* __restrict__ gsum) {
    int blk = blockIdx.x;
    int b = blk >> 6;
    int g = (blk >> 1) & 31;
    int h = blk & 1;
    int d4 = (h << 8) + (threadIdx.x << 2);     // h*256 + tid*4

    const float* src = fe + ((size_t)(b * T + g * (GRP * CHUNK)) * D + d4);
    float* cpb = cp + ((size_t)b * NCHUNK + (size_t)g * GRP) * D + d4;

    float4 acc = {0.f, 0.f, 0.f, 0.f};
#pragma unroll 2
    for (int c = 0; c < GRP; ++c) {
#pragma unroll
        for (int r = 0; r < CHUNK; ++r) {
            float4 v = *(const float4*)(src + (size_t)(c * CHUNK + r) * D);
            acc.x += v.x; acc.y += v.y; acc.z += v.z; acc.w += v.w;
        }
        *(float4*)(cpb + (size_t)c * D) = acc;
    }
    *(float4*)(gsum + ((size_t)b * NGRP + g) * D + d4) = acc;
}

// ---------------- K2b: exclusive scan of the 32 coarse totals per batch ------
__global__ __launch_bounds__(128) void k_scan_coarse(const float* __restrict__ gsum,
                                                     float* __restrict__ gx) {
    int b = blockIdx.x;
    int d4 = threadIdx.x << 2;
    float4 acc = {0.f, 0.f, 0.f, 0.f};
#pragma unroll
    for (int g = 0; g < NGRP; ++g) {
        *(float4*)(gx + ((size_t)b * (NGRP + 1) + g) * D + d4) = acc;
        float4 v = *(const float4*)(gsum + ((size_t)b * NGRP + g) * D + d4);
        acc.x += v.x; acc.y += v.y; acc.z += v.z; acc.w += v.w;
    }
    *(float4*)(gx + ((size_t)b * (NGRP + 1) + NGRP) * D + d4) = acc;
}

// ---------------- K3: segment means + fourier -> X[4096, 544] ----------------
// chunk-prefix(c) = gx[b, c>>4] + (c&15 ? cp[b, c-1] : 0)
__global__ __launch_bounds__(128) void k_buildx(const float* __restrict__ fe,
                                                const int* __restrict__ bounds,
                                                const float* __restrict__ cp,
                                                const float* __restrict__ gx,
                                                float* __restrict__ X) {
    int bm = blockIdx.x;
    int b = bm / M;
    int m = bm % M;
    int b0 = bounds[bm * 2 + 0];
    int b1 = bounds[bm * 2 + 1];
    int s = min(max(b0, 0), T - 1);
    int e = max(min(b1, T), s + 1);
    int cs_ = s >> 4, ce = e >> 4;
    int d4 = threadIdx.x << 2;

    const float* cpb = cp + (size_t)b * NCHUNK * D;
    const float* gxb = gx + (size_t)b * (NGRP + 1) * D;

    float4 acc = *(const float4*)(gxb + (size_t)(ce >> 4) * D + d4);
    if (ce & 15) {
        float4 v = *(const float4*)(cpb + (size_t)(ce - 1) * D + d4);
        acc.x += v.x; acc.y += v.y; acc.z += v.z; acc.w += v.w;
    }
    {
        float4 p = *(const float4*)(gxb + (size_t)(cs_ >> 4) * D + d4);
        acc.x -= p.x; acc.y -= p.y; acc.z -= p.z; acc.w -= p.w;
        if (cs_ & 15) {
            float4 v = *(const float4*)(cpb + (size_t)(cs_ - 1) * D + d4);
            acc.x -= v.x; acc.y -= v.y; acc.z -= v.z; acc.w -= v.w;
        }
    }

    const float* feb = fe + (size_t)b * T * D + d4;
    for (int t = ce * CHUNK; t < e; ++t) {
        float4 v = *(const float4*)(feb + (size_t)t * D);
        acc.x += v.x; acc.y += v.y; acc.z += v.z; acc.w += v.w;
    }
    for (int t = cs_ * CHUNK; t < s; ++t) {
        float4 v = *(const float4*)(feb + (size_t)t * D);
        acc.x -= v.x; acc.y -= v.y; acc.z -= v.z; acc.w -= v.w;
    }
    float inv = 1.0f / (float)(e - s);
    acc.x *= inv; acc.y *= inv; acc.z *= inv; acc.w *= inv;

    float* xr = X + (size_t)bm * KIN;
    *(float4*)(xr + d4) = acc;

    int t = threadIdx.x;
    if (t < POS) {
        int i = t & 15;
        float freq = expf(0.46051701859880914f * (float)i);  // 1000^(i/15)
        float pos = (float)m * (1.0f / 511.0f);
        float ang = pos * freq;
        xr[D + t] = (t < 16) ? sinf(ang) : cosf(ang);
    }
}

// ---------------- K4: Out[4096,512] = X[4096,544] @ W[544,512] + b ----------
// fp32 vector GEMM, 64x64 tile, 256 threads, 4x4 microkernel, grid 512 blocks
// (2 blocks/CU -> cross-block overlap hides barrier/LDS stalls)
#define TM 64
#define TN 64
#define TKc 16
__global__ __launch_bounds__(256) void k_gemm(const float* __restrict__ X,
                                              const float* __restrict__ W,
                                              const float* __restrict__ bias,
                                              float* __restrict__ out) {
    __shared__ float Xs[TKc][TM + 4];
    __shared__ float Ws[TKc][TN + 4];
    int n0 = blockIdx.x * TN;
    int m0 = blockIdx.y * TM;
    int tid = threadIdx.x;
    int tx = tid & 15, ty = tid >> 4;

    float acc[4][4] = {{0.f}};

    for (int k0 = 0; k0 < KIN; k0 += TKc) {  // 34 iterations
        {
            // X tile: 64 rows x 16 k, transposed into Xs[k][m]
            int row = tid >> 2;
            int kq = (tid & 3) << 2;
            float4 v = *(const float4*)(X + (size_t)(m0 + row) * KIN + k0 + kq);
            Xs[kq + 0][row] = v.x;
            Xs[kq + 1][row] = v.y;
            Xs[kq + 2][row] = v.z;
            Xs[kq + 3][row] = v.w;
            // W tile: 16 rows x 64 cols
            float4 w = *(const float4*)(W + (size_t)(k0 + ty) * D + n0 + (tx << 2));
            *(float4*)&Ws[ty][tx << 2] = w;
        }
        __syncthreads();
#pragma unroll
        for (int k = 0; k < TKc; ++k) {
            float4 a = *(const float4*)&Xs[k][ty << 2];
            float4 w4 = *(const float4*)&Ws[k][tx << 2];
            acc[0][0] += a.x * w4.x; acc[0][1] += a.x * w4.y; acc[0][2] += a.x * w4.z; acc[0][3] += a.x * w4.w;
            acc[1][0] += a.y * w4.x; acc[1][1] += a.y * w4.y; acc[1][2] += a.y * w4.z; acc[1][3] += a.y * w4.w;
            acc[2][0] += a.z * w4.x; acc[2][1] += a.z * w4.y; acc[2][2] += a.z * w4.z; acc[2][3] += a.z * w4.w;
            acc[3][0] += a.w * w4.x; acc[3][1] += a.w * w4.y; acc[3][2] += a.w * w4.z; acc[3][3] += a.w * w4.w;
        }
        __syncthreads();
    }

    float4 bv = *(const float4*)(bias + n0 + (tx << 2));
#pragma unroll
    for (int i = 0; i < 4; ++i) {
        float4 o;
        o.x = acc[i][0] + bv.x;
        o.y = acc[i][1] + bv.y;
        o.z = acc[i][2] + bv.z;
        o.w = acc[i][3] + bv.w;
        *(float4*)(out + (size_t)(m0 + (ty << 2) + i) * D + n0 + (tx << 2)) = o;
    }
}

extern "C" void kernel_launch(void* const* d_in, const int* in_sizes, int n_in,
                              void* d_out, int out_size, void* d_ws, size_t ws_size,
                              hipStream_t stream) {
    const float* fe = (const float*)d_in[0];
    const int* bounds = (const int*)d_in[1];
    const float* W = (const float*)d_in[2];
    const float* bias = (const float*)d_in[3];
    float* out = (float*)d_out;

    float* cp = (float*)d_ws;                                  // B*512*D = 8.4 MB
    float* gsum = cp + (size_t)B * NCHUNK * D;                 // B*32*D = 512 KB
    float* gx = gsum + (size_t)B * NGRP * D;                   // B*33*D = 528 KB
    float* X = gx + (size_t)B * (NGRP + 1) * D;                // BM*KIN = 8.9 MB

    k_scanchunk<<<B * NGRP * 2, 64, 0, stream>>>(fe, cp, gsum);
    k_scan_coarse<<<B, 128, 0, stream>>>(gsum, gx);
    k_buildx<<<BM, 128, 0, stream>>>(fe, bounds, cp, gx, X);
    dim3 g(D / TN, BM / TM);
    k_gemm<<<g, 256, 0, stream>>>(X, W, bias, out);
}

// Round 4
// 248.100 us; speedup vs baseline: 1.2150x; 1.0797x over previous
//
#include <hip/hip_runtime.h>
#include <math.h>

#define B 8
#define T 8192
#define D 512
#define M 512
#define POS 32
#define CHUNK 16
#define NCHUNK (T / CHUNK)     // 512 fine chunks per batch
#define GRP 16
#define NGRP (NCHUNK / GRP)    // 32
#define BM (B * M)             // 4096
#define KD 512                 // GEMM K (fourier part hoisted out)

typedef __attribute__((ext_vector_type(8))) short short8;
typedef __attribute__((ext_vector_type(4))) float floatx4;

static __device__ inline unsigned short f2bf(float f) {
    unsigned int u = __float_as_uint(f);
    unsigned int r = (u + 0x7fffu + ((u >> 16) & 1u)) >> 16;   // RNE
    return (unsigned short)r;
}
static __device__ inline float bf2f(unsigned short h) {
    return __uint_as_float(((unsigned int)h) << 16);
}

// ---------------- K1: fused chunk-sum + intra-group inclusive scan ----------
__global__ __launch_bounds__(64) void k_scanchunk(const float* __restrict__ fe,
                                                  float* __restrict__ cp,
                                                  float* __restrict__ gsum) {
    int blk = blockIdx.x;
    int b = blk >> 6;
    int g = (blk >> 1) & 31;
    int h = blk & 1;
    int d4 = (h << 8) + (threadIdx.x << 2);

    const float* src = fe + ((size_t)(b * T + g * (GRP * CHUNK)) * D + d4);
    float* cpb = cp + ((size_t)b * NCHUNK + (size_t)g * GRP) * D + d4;

    float4 acc = {0.f, 0.f, 0.f, 0.f};
#pragma unroll 2
    for (int c = 0; c < GRP; ++c) {
#pragma unroll
        for (int r = 0; r < CHUNK; ++r) {
            float4 v = *(const float4*)(src + (size_t)(c * CHUNK + r) * D);
            acc.x += v.x; acc.y += v.y; acc.z += v.z; acc.w += v.w;
        }
        *(float4*)(cpb + (size_t)c * D) = acc;
    }
    *(float4*)(gsum + ((size_t)b * NGRP + g) * D + d4) = acc;
}

// ---------------- K2b: exclusive scan of 32 coarse totals per batch ---------
__global__ __launch_bounds__(128) void k_scan_coarse(const float* __restrict__ gsum,
                                                     float* __restrict__ gx) {
    int b = blockIdx.x;
    int d4 = threadIdx.x << 2;
    float4 acc = {0.f, 0.f, 0.f, 0.f};
#pragma unroll
    for (int g = 0; g < NGRP; ++g) {
        *(float4*)(gx + ((size_t)b * (NGRP + 1) + g) * D + d4) = acc;
        float4 v = *(const float4*)(gsum + ((size_t)b * NGRP + g) * D + d4);
        acc.x += v.x; acc.y += v.y; acc.z += v.z; acc.w += v.w;
    }
    *(float4*)(gx + ((size_t)b * (NGRP + 1) + NGRP) * D + d4) = acc;
}

// ---------------- W split+transpose: W[0:512][0:512] -> WhT/WlT [n][k] bf16 --
__global__ __launch_bounds__(256) void k_wsplit(const float* __restrict__ W,
                                                short* __restrict__ WhT,
                                                short* __restrict__ WlT) {
    __shared__ float ws[32][65];
    int k0 = (blockIdx.x & 15) * 32;
    int n0 = (blockIdx.x >> 4) * 64;
    int t = threadIdx.x;
    {
        int kk = t >> 3;
        int nn = (t & 7) << 3;
        const float* src = W + (size_t)(k0 + kk) * D + n0 + nn;
        float4 v0 = *(const float4*)src;
        float4 v1 = *(const float4*)(src + 4);
        ws[kk][nn + 0] = v0.x; ws[kk][nn + 1] = v0.y; ws[kk][nn + 2] = v0.z; ws[kk][nn + 3] = v0.w;
        ws[kk][nn + 4] = v1.x; ws[kk][nn + 5] = v1.y; ws[kk][nn + 6] = v1.z; ws[kk][nn + 7] = v1.w;
    }
    __syncthreads();
    int n = t >> 2;
    int kq = (t & 3) << 3;
    short8 hv, lv;
#pragma unroll
    for (int j = 0; j < 8; ++j) {
        float w = ws[kq + j][n];
        unsigned short hb = f2bf(w);
        hv[j] = (short)hb;
        lv[j] = (short)f2bf(w - bf2f(hb));
    }
    size_t off = (size_t)(n0 + n) * KD + k0 + kq;
    *(short8*)(WhT + off) = hv;
    *(short8*)(WlT + off) = lv;
}

// ---------------- ffout[m][n] = FF(m) @ W[512:544] + b ----------------------
__global__ __launch_bounds__(128) void k_ffout(const float* __restrict__ W,
                                               const float* __restrict__ bias,
                                               float* __restrict__ ffout) {
    int m = blockIdx.x;
    int n4 = threadIdx.x << 2;
    float pos = (float)m * (1.0f / 511.0f);
    float4 acc = *(const float4*)(bias + n4);
#pragma unroll
    for (int j = 0; j < 16; ++j) {
        float freq = expf(0.46051701859880914f * (float)j);  // 1000^(j/15)
        float ang = pos * freq;
        float s = sinf(ang), c = cosf(ang);
        float4 wsn = *(const float4*)(W + (size_t)(D + j) * D + n4);
        float4 wcn = *(const float4*)(W + (size_t)(D + 16 + j) * D + n4);
        acc.x += s * wsn.x + c * wcn.x;
        acc.y += s * wsn.y + c * wcn.y;
        acc.z += s * wsn.z + c * wcn.z;
        acc.w += s * wsn.w + c * wcn.w;
    }
    *(float4*)(ffout + (size_t)m * D + n4) = acc;
}

// ---------------- K3: segment means -> Xh/Xl [4096][512] bf16 ---------------
__global__ __launch_bounds__(128) void k_buildx(const float* __restrict__ fe,
                                                const int* __restrict__ bounds,
                                                const float* __restrict__ cp,
                                                const float* __restrict__ gx,
                                                short* __restrict__ Xh,
                                                short* __restrict__ Xl) {
    int bm = blockIdx.x;
    int b = bm / M;
    int b0 = bounds[bm * 2 + 0];
    int b1 = bounds[bm * 2 + 1];
    int s = min(max(b0, 0), T - 1);
    int e = max(min(b1, T), s + 1);
    int cs_ = s >> 4, ce = e >> 4;
    int d4 = threadIdx.x << 2;

    const float* cpb = cp + (size_t)b * NCHUNK * D;
    const float* gxb = gx + (size_t)b * (NGRP + 1) * D;

    float4 acc = *(const float4*)(gxb + (size_t)(ce >> 4) * D + d4);
    if (ce & 15) {
        float4 v = *(const float4*)(cpb + (size_t)(ce - 1) * D + d4);
        acc.x += v.x; acc.y += v.y; acc.z += v.z; acc.w += v.w;
    }
    {
        float4 p = *(const float4*)(gxb + (size_t)(cs_ >> 4) * D + d4);
        acc.x -= p.x; acc.y -= p.y; acc.z -= p.z; acc.w -= p.w;
        if (cs_ & 15) {
            float4 v = *(const float4*)(cpb + (size_t)(cs_ - 1) * D + d4);
            acc.x -= v.x; acc.y -= v.y; acc.z -= v.z; acc.w -= v.w;
        }
    }

    const float* feb = fe + (size_t)b * T * D + d4;
    for (int t = ce * CHUNK; t < e; ++t) {
        float4 v = *(const float4*)(feb + (size_t)t * D);
        acc.x += v.x; acc.y += v.y; acc.z += v.z; acc.w += v.w;
    }
    for (int t = cs_ * CHUNK; t < s; ++t) {
        float4 v = *(const float4*)(feb + (size_t)t * D);
        acc.x -= v.x; acc.y -= v.y; acc.z -= v.z; acc.w -= v.w;
    }
    float inv = 1.0f / (float)(e - s);
    float x0 = acc.x * inv, x1 = acc.y * inv, x2 = acc.z * inv, x3 = acc.w * inv;

    unsigned short h0 = f2bf(x0), h1 = f2bf(x1), h2 = f2bf(x2), h3 = f2bf(x3);
    typedef __attribute__((ext_vector_type(4))) short short4v;
    short4v hv, lv;
    hv[0] = (short)h0; hv[1] = (short)h1; hv[2] = (short)h2; hv[3] = (short)h3;
    lv[0] = (short)f2bf(x0 - bf2f(h0));
    lv[1] = (short)f2bf(x1 - bf2f(h1));
    lv[2] = (short)f2bf(x2 - bf2f(h2));
    lv[3] = (short)f2bf(x3 - bf2f(h3));
    size_t off = (size_t)bm * KD + d4;
    *(short4v*)(Xh + off) = hv;
    *(short4v*)(Xl + off) = lv;
}

// ---------------- K4: MFMA GEMM, Out = (Xh+Xl)@(Wh+Wl) + ffout --------------
// 64x64 block tile, 256 threads (4 waves in 2x2 of 32x32 wave-tiles), K=512.
// LDS tiles 64 rows x 32 k bf16, 16B-quad XOR swizzle (q ^= (row>>1)&3).
__global__ __launch_bounds__(256) void k_gemm(const short* __restrict__ Xh,
                                              const short* __restrict__ Xl,
                                              const short* __restrict__ WhT,
                                              const short* __restrict__ WlT,
                                              const float* __restrict__ ffout,
                                              float* __restrict__ out) {
    __shared__ short Ah[64 * 32], Al[64 * 32], Bh[64 * 32], Bl[64 * 32];
    int n0 = (blockIdx.x & 7) << 6;
    int m0 = (blockIdx.x >> 3) << 6;
    int tid = threadIdx.x;
    int w = tid >> 6;
    int l = tid & 63;
    int lm = l & 15;
    int q = l >> 4;
    int wm = (w & 1) << 5;       // wave m offset 0/32
    int wn = (w >> 1) << 5;      // wave n offset 0/32

    floatx4 acc[2][2];
#pragma unroll
    for (int i = 0; i < 2; ++i)
#pragma unroll
        for (int j = 0; j < 2; ++j)
            acc[i][j] = (floatx4){0.f, 0.f, 0.f, 0.f};

    // staging: thread -> row tid>>2 (0..63), k-quad tid&3 (8 bf16 = 16B)
    int srow = tid >> 2;
    int skq = tid & 3;
    int sslot = skq ^ ((srow >> 1) & 3);
    int ldsoff = (srow << 5) + (sslot << 3);
    const short* gXh = Xh + (size_t)(m0 + srow) * KD + (skq << 3);
    const short* gXl = Xl + (size_t)(m0 + srow) * KD + (skq << 3);
    const short* gBh = WhT + (size_t)(n0 + srow) * KD + (skq << 3);
    const short* gBl = WlT + (size_t)(n0 + srow) * KD + (skq << 3);

    // fragment read offsets (2 m-rows, 2 n-rows per wave)
    int aoff[2], boff[2];
#pragma unroll
    for (int mt = 0; mt < 2; ++mt) {
        int row = wm + (mt << 4) + lm;
        aoff[mt] = (row << 5) + ((q ^ ((row >> 1) & 3)) << 3);
    }
#pragma unroll
    for (int nt = 0; nt < 2; ++nt) {
        int row = wn + (nt << 4) + lm;
        boff[nt] = (row << 5) + ((q ^ ((row >> 1) & 3)) << 3);
    }

    for (int k0 = 0; k0 < KD; k0 += 32) {
        short8 vxh = *(const short8*)(gXh + k0);
        short8 vxl = *(const short8*)(gXl + k0);
        short8 vbh = *(const short8*)(gBh + k0);
        short8 vbl = *(const short8*)(gBl + k0);
        __syncthreads();
        *(short8*)(Ah + ldsoff) = vxh;
        *(short8*)(Al + ldsoff) = vxl;
        *(short8*)(Bh + ldsoff) = vbh;
        *(short8*)(Bl + ldsoff) = vbl;
        __syncthreads();

        short8 ah[2], al[2], bh[2], bl[2];
#pragma unroll
        for (int mt = 0; mt < 2; ++mt) {
            ah[mt] = *(const short8*)(Ah + aoff[mt]);
            al[mt] = *(const short8*)(Al + aoff[mt]);
        }
#pragma unroll
        for (int nt = 0; nt < 2; ++nt) {
            bh[nt] = *(const short8*)(Bh + boff[nt]);
            bl[nt] = *(const short8*)(Bl + boff[nt]);
        }
#pragma unroll
        for (int mt = 0; mt < 2; ++mt)
#pragma unroll
            for (int nt = 0; nt < 2; ++nt) {
                acc[mt][nt] = __builtin_amdgcn_mfma_f32_16x16x32_bf16(
                    ah[mt], bh[nt], acc[mt][nt], 0, 0, 0);
                acc[mt][nt] = __builtin_amdgcn_mfma_f32_16x16x32_bf16(
                    ah[mt], bl[nt], acc[mt][nt], 0, 0, 0);
                acc[mt][nt] = __builtin_amdgcn_mfma_f32_16x16x32_bf16(
                    al[mt], bh[nt], acc[mt][nt], 0, 0, 0);
            }
    }

    // epilogue: D[row=q*4+r][col=lm] per tile; add ffout[m & 511][n]
#pragma unroll
    for (int mt = 0; mt < 2; ++mt) {
#pragma unroll
        for (int nt = 0; nt < 2; ++nt) {
            int gcol = n0 + wn + (nt << 4) + lm;
#pragma unroll
            for (int r = 0; r < 4; ++r) {
                int grow = m0 + wm + (mt << 4) + (q << 2) + r;
                float f = ffout[(size_t)(grow & (M - 1)) * D + gcol];
                out[(size_t)grow * D + gcol] = acc[mt][nt][r] + f;
            }
        }
    }
}

extern "C" void kernel_launch(void* const* d_in, const int* in_sizes, int n_in,
                              void* d_out, int out_size, void* d_ws, size_t ws_size,
                              hipStream_t stream) {
    const float* fe = (const float*)d_in[0];
    const int* bounds = (const int*)d_in[1];
    const float* W = (const float*)d_in[2];
    const float* bias = (const float*)d_in[3];
    float* out = (float*)d_out;

    float* cp = (float*)d_ws;                                  // 8*512*512 f32 = 8.4 MB
    float* gsum = cp + (size_t)B * NCHUNK * D;                 // 512 KB
    float* gx = gsum + (size_t)B * NGRP * D;                   // 528 KB
    float* ffout = gx + (size_t)B * (NGRP + 1) * D;            // 512*512 f32 = 1 MB
    short* Xh = (short*)(ffout + (size_t)M * D);               // 4 MB
    short* Xl = Xh + (size_t)BM * KD;                          // 4 MB
    short* WhT = Xl + (size_t)BM * KD;                         // 512 KB
    short* WlT = WhT + (size_t)KD * D;                         // 512 KB

    k_scanchunk<<<B * NGRP * 2, 64, 0, stream>>>(fe, cp, gsum);
    k_scan_coarse<<<B, 128, 0, stream>>>(gsum, gx);
    k_wsplit<<<128, 256, 0, stream>>>(W, WhT, WlT);
    k_ffout<<<M, 128, 0, stream>>>(W, bias, ffout);
    k_buildx<<<BM, 128, 0, stream>>>(fe, bounds, cp, gx, Xh, Xl);
    k_gemm<<<64 * 8, 256, 0, stream>>>(Xh, Xl, WhT, WlT, ffout, out);
}

// Round 5
// 230.655 us; speedup vs baseline: 1.3069x; 1.0756x over previous
//
#include <hip/hip_runtime.h>
#include <math.h>

#define B 8
#define T 8192
#define D 512
#define M 512
#define POS 32
#define CHUNK 4
#define NCHUNK (T / CHUNK)     // 2048 fine chunks per batch
#define GRP 32                 // fine chunks per coarse group
#define NGRP (NCHUNK / GRP)    // 64 groups per batch
#define BM (B * M)             // 4096
#define KD 512                 // GEMM K (fourier part hoisted out)

typedef __attribute__((ext_vector_type(8))) short short8;
typedef __attribute__((ext_vector_type(4))) short short4v;
typedef __attribute__((ext_vector_type(4))) float floatx4;

static __device__ inline unsigned short f2bf(float f) {
    unsigned int u = __float_as_uint(f);
    unsigned int r = (u + 0x7fffu + ((u >> 16) & 1u)) >> 16;   // RNE
    return (unsigned short)r;
}
static __device__ inline float bf2f(unsigned short h) {
    return __uint_as_float(((unsigned int)h) << 16);
}

// ================= KA: fused {chunk-scan | wsplit | ffout} ==================
// blocks [0,512): (b,g) chunk sums (CHUNK=4) + inclusive scan within group of 32
// blocks [512,640): W[0:512][:] -> WhT/WlT bf16 [n][k]
// blocks [640,896): ffout[m][n] = FF(m) @ W[512:544] + b
__global__ __launch_bounds__(256) void k_fusedA(const float* __restrict__ fe,
                                                const float* __restrict__ W,
                                                const float* __restrict__ bias,
                                                float* __restrict__ cp,
                                                float* __restrict__ gsum,
                                                short* __restrict__ WhT,
                                                short* __restrict__ WlT,
                                                float* __restrict__ ffout) {
    int blk = blockIdx.x;
    int tid = threadIdx.x;
    if (blk < 512) {
        // ---- chunk-scan: b = blk>>6, g = blk&63, 128 rows, full D (float2)
        int b = blk >> 6;
        int g = blk & 63;
        int d2 = tid << 1;
        const float* src = fe + ((size_t)(b * T + g * (GRP * CHUNK)) * D + d2);
        float* cpb = cp + ((size_t)b * NCHUNK + (size_t)g * GRP) * D + d2;
        float2 acc = {0.f, 0.f};
#pragma unroll 4
        for (int c = 0; c < GRP; ++c) {
#pragma unroll
            for (int r = 0; r < CHUNK; ++r) {
                float2 v = *(const float2*)(src + (size_t)(c * CHUNK + r) * D);
                acc.x += v.x; acc.y += v.y;
            }
            *(float2*)(cpb + (size_t)c * D) = acc;
        }
        *(float2*)(gsum + ((size_t)b * NGRP + g) * D + d2) = acc;
    } else if (blk < 640) {
        // ---- wsplit
        __shared__ float ws[32][65];
        int wb = blk - 512;
        int k0 = (wb & 15) * 32;
        int n0 = (wb >> 4) * 64;
        {
            int kk = tid >> 3;
            int nn = (tid & 7) << 3;
            const float* src = W + (size_t)(k0 + kk) * D + n0 + nn;
            float4 v0 = *(const float4*)src;
            float4 v1 = *(const float4*)(src + 4);
            ws[kk][nn + 0] = v0.x; ws[kk][nn + 1] = v0.y; ws[kk][nn + 2] = v0.z; ws[kk][nn + 3] = v0.w;
            ws[kk][nn + 4] = v1.x; ws[kk][nn + 5] = v1.y; ws[kk][nn + 6] = v1.z; ws[kk][nn + 7] = v1.w;
        }
        __syncthreads();
        int n = tid >> 2;
        int kq = (tid & 3) << 3;
        short8 hv, lv;
#pragma unroll
        for (int j = 0; j < 8; ++j) {
            float w = ws[kq + j][n];
            unsigned short hb = f2bf(w);
            hv[j] = (short)hb;
            lv[j] = (short)f2bf(w - bf2f(hb));
        }
        size_t off = (size_t)(n0 + n) * KD + k0 + kq;
        *(short8*)(WhT + off) = hv;
        *(short8*)(WlT + off) = lv;
    } else {
        // ---- ffout: 2 m per block
        int m = ((blk - 640) << 1) + (tid >> 7);
        int n4 = (tid & 127) << 2;
        float pos = (float)m * (1.0f / 511.0f);
        float4 acc = *(const float4*)(bias + n4);
#pragma unroll
        for (int j = 0; j < 16; ++j) {
            float freq = expf(0.46051701859880914f * (float)j);  // 1000^(j/15)
            float ang = pos * freq;
            float s = sinf(ang), c = cosf(ang);
            float4 wsn = *(const float4*)(W + (size_t)(D + j) * D + n4);
            float4 wcn = *(const float4*)(W + (size_t)(D + 16 + j) * D + n4);
            acc.x += s * wsn.x + c * wcn.x;
            acc.y += s * wsn.y + c * wcn.y;
            acc.z += s * wsn.z + c * wcn.z;
            acc.w += s * wsn.w + c * wcn.w;
        }
        *(float4*)(ffout + (size_t)m * D + n4) = acc;
    }
}

// ================= KB: exclusive scan of 64 coarse totals per batch =========
__global__ __launch_bounds__(256) void k_scan_coarse(const float* __restrict__ gsum,
                                                     float* __restrict__ gx) {
    int b = blockIdx.x;
    int d2 = threadIdx.x << 1;
    float2 acc = {0.f, 0.f};
#pragma unroll
    for (int g = 0; g < NGRP; ++g) {
        *(float2*)(gx + ((size_t)b * (NGRP + 1) + g) * D + d2) = acc;
        float2 v = *(const float2*)(gsum + ((size_t)b * NGRP + g) * D + d2);
        acc.x += v.x; acc.y += v.y;
    }
    *(float2*)(gx + ((size_t)b * (NGRP + 1) + NGRP) * D + d2) = acc;
}

// ================= KC: segment means -> Xh/Xl [4096][512] bf16 ==============
// chunk-prefix(c) = gx[b, c>>5] + (c&31 ? cp[b, c-1] : 0);  CHUNK=4 edges
__global__ __launch_bounds__(128) void k_buildx(const float* __restrict__ fe,
                                                const int* __restrict__ bounds,
                                                const float* __restrict__ cp,
                                                const float* __restrict__ gx,
                                                short* __restrict__ Xh,
                                                short* __restrict__ Xl) {
    int bm = blockIdx.x;
    int b = bm / M;
    int b0 = bounds[bm * 2 + 0];
    int b1 = bounds[bm * 2 + 1];
    int s = min(max(b0, 0), T - 1);
    int e = max(min(b1, T), s + 1);
    int cs_ = s >> 2, ce = e >> 2;
    int d4 = threadIdx.x << 2;

    const float* cpb = cp + (size_t)b * NCHUNK * D;
    const float* gxb = gx + (size_t)b * (NGRP + 1) * D;

    float4 acc = *(const float4*)(gxb + (size_t)(ce >> 5) * D + d4);
    if (ce & 31) {
        float4 v = *(const float4*)(cpb + (size_t)(ce - 1) * D + d4);
        acc.x += v.x; acc.y += v.y; acc.z += v.z; acc.w += v.w;
    }
    {
        float4 p = *(const float4*)(gxb + (size_t)(cs_ >> 5) * D + d4);
        acc.x -= p.x; acc.y -= p.y; acc.z -= p.z; acc.w -= p.w;
        if (cs_ & 31) {
            float4 v = *(const float4*)(cpb + (size_t)(cs_ - 1) * D + d4);
            acc.x -= v.x; acc.y -= v.y; acc.z -= v.z; acc.w -= v.w;
        }
    }

    const float* feb = fe + (size_t)b * T * D + d4;
    for (int t = ce * CHUNK; t < e; ++t) {           // <= 3 iters
        float4 v = *(const float4*)(feb + (size_t)t * D);
        acc.x += v.x; acc.y += v.y; acc.z += v.z; acc.w += v.w;
    }
    for (int t = cs_ * CHUNK; t < s; ++t) {          // <= 3 iters
        float4 v = *(const float4*)(feb + (size_t)t * D);
        acc.x -= v.x; acc.y -= v.y; acc.z -= v.z; acc.w -= v.w;
    }
    float inv = 1.0f / (float)(e - s);
    float x0 = acc.x * inv, x1 = acc.y * inv, x2 = acc.z * inv, x3 = acc.w * inv;

    unsigned short h0 = f2bf(x0), h1 = f2bf(x1), h2 = f2bf(x2), h3 = f2bf(x3);
    short4v hv, lv;
    hv[0] = (short)h0; hv[1] = (short)h1; hv[2] = (short)h2; hv[3] = (short)h3;
    lv[0] = (short)f2bf(x0 - bf2f(h0));
    lv[1] = (short)f2bf(x1 - bf2f(h1));
    lv[2] = (short)f2bf(x2 - bf2f(h2));
    lv[3] = (short)f2bf(x3 - bf2f(h3));
    size_t off = (size_t)bm * KD + d4;
    *(short4v*)(Xh + off) = hv;
    *(short4v*)(Xl + off) = lv;
}

// ================= KD: MFMA GEMM, Out = (Xh+Xl)@(Wh+Wl) + ffout =============
// 64x64 block tile, 256 threads (2x2 waves of 32x32), K=512, XOR-swizzled LDS.
__global__ __launch_bounds__(256) void k_gemm(const short* __restrict__ Xh,
                                              const short* __restrict__ Xl,
                                              const short* __restrict__ WhT,
                                              const short* __restrict__ WlT,
                                              const float* __restrict__ ffout,
                                              float* __restrict__ out) {
    __shared__ short Ah[64 * 32], Al[64 * 32], Bh[64 * 32], Bl[64 * 32];
    int n0 = (blockIdx.x & 7) << 6;
    int m0 = (blockIdx.x >> 3) << 6;
    int tid = threadIdx.x;
    int w = tid >> 6;
    int l = tid & 63;
    int lm = l & 15;
    int q = l >> 4;
    int wm = (w & 1) << 5;
    int wn = (w >> 1) << 5;

    floatx4 acc[2][2];
#pragma unroll
    for (int i = 0; i < 2; ++i)
#pragma unroll
        for (int j = 0; j < 2; ++j)
            acc[i][j] = (floatx4){0.f, 0.f, 0.f, 0.f};

    int srow = tid >> 2;
    int skq = tid & 3;
    int sslot = skq ^ ((srow >> 1) & 3);
    int ldsoff = (srow << 5) + (sslot << 3);
    const short* gXh = Xh + (size_t)(m0 + srow) * KD + (skq << 3);
    const short* gXl = Xl + (size_t)(m0 + srow) * KD + (skq << 3);
    const short* gBh = WhT + (size_t)(n0 + srow) * KD + (skq << 3);
    const short* gBl = WlT + (size_t)(n0 + srow) * KD + (skq << 3);

    int aoff[2], boff[2];
#pragma unroll
    for (int mt = 0; mt < 2; ++mt) {
        int row = wm + (mt << 4) + lm;
        aoff[mt] = (row << 5) + ((q ^ ((row >> 1) & 3)) << 3);
    }
#pragma unroll
    for (int nt = 0; nt < 2; ++nt) {
        int row = wn + (nt << 4) + lm;
        boff[nt] = (row << 5) + ((q ^ ((row >> 1) & 3)) << 3);
    }

    for (int k0 = 0; k0 < KD; k0 += 32) {
        short8 vxh = *(const short8*)(gXh + k0);
        short8 vxl = *(const short8*)(gXl + k0);
        short8 vbh = *(const short8*)(gBh + k0);
        short8 vbl = *(const short8*)(gBl + k0);
        __syncthreads();
        *(short8*)(Ah + ldsoff) = vxh;
        *(short8*)(Al + ldsoff) = vxl;
        *(short8*)(Bh + ldsoff) = vbh;
        *(short8*)(Bl + ldsoff) = vbl;
        __syncthreads();

        short8 ah[2], al[2], bh[2], bl[2];
#pragma unroll
        for (int mt = 0; mt < 2; ++mt) {
            ah[mt] = *(const short8*)(Ah + aoff[mt]);
            al[mt] = *(const short8*)(Al + aoff[mt]);
        }
#pragma unroll
        for (int nt = 0; nt < 2; ++nt) {
            bh[nt] = *(const short8*)(Bh + boff[nt]);
            bl[nt] = *(const short8*)(Bl + boff[nt]);
        }
#pragma unroll
        for (int mt = 0; mt < 2; ++mt)
#pragma unroll
            for (int nt = 0; nt < 2; ++nt) {
                acc[mt][nt] = __builtin_amdgcn_mfma_f32_16x16x32_bf16(
                    ah[mt], bh[nt], acc[mt][nt], 0, 0, 0);
                acc[mt][nt] = __builtin_amdgcn_mfma_f32_16x16x32_bf16(
                    ah[mt], bl[nt], acc[mt][nt], 0, 0, 0);
                acc[mt][nt] = __builtin_amdgcn_mfma_f32_16x16x32_bf16(
                    al[mt], bh[nt], acc[mt][nt], 0, 0, 0);
            }
    }

#pragma unroll
    for (int mt = 0; mt < 2; ++mt) {
#pragma unroll
        for (int nt = 0; nt < 2; ++nt) {
            int gcol = n0 + wn + (nt << 4) + lm;
#pragma unroll
            for (int r = 0; r < 4; ++r) {
                int grow = m0 + wm + (mt << 4) + (q << 2) + r;
                float f = ffout[(size_t)(grow & (M - 1)) * D + gcol];
                out[(size_t)grow * D + gcol] = acc[mt][nt][r] + f;
            }
        }
    }
}

extern "C" void kernel_launch(void* const* d_in, const int* in_sizes, int n_in,
                              void* d_out, int out_size, void* d_ws, size_t ws_size,
                              hipStream_t stream) {
    const float* fe = (const float*)d_in[0];
    const int* bounds = (const int*)d_in[1];
    const float* W = (const float*)d_in[2];
    const float* bias = (const float*)d_in[3];
    float* out = (float*)d_out;

    float* cp = (float*)d_ws;                                  // 8*2048*512 f32 = 33.5 MB
    float* gsum = cp + (size_t)B * NCHUNK * D;                 // 8*64*512 = 1 MB
    float* gx = gsum + (size_t)B * NGRP * D;                   // 8*65*512 = 1.06 MB
    float* ffout = gx + (size_t)B * (NGRP + 1) * D;            // 1 MB
    short* Xh = (short*)(ffout + (size_t)M * D);               // 4 MB
    short* Xl = Xh + (size_t)BM * KD;                          // 4 MB
    short* WhT = Xl + (size_t)BM * KD;                         // 0.5 MB
    short* WlT = WhT + (size_t)KD * D;                         // 0.5 MB

    k_fusedA<<<896, 256, 0, stream>>>(fe, W, bias, cp, gsum, WhT, WlT, ffout);
    k_scan_coarse<<<B, 256, 0, stream>>>(gsum, gx);
    k_buildx<<<BM, 128, 0, stream>>>(fe, bounds, cp, gx, Xh, Xl);
    k_gemm<<<64 * 8, 256, 0, stream>>>(Xh, Xl, WhT, WlT, ffout, out);
}

// Round 6
// 227.265 us; speedup vs baseline: 1.3264x; 1.0149x over previous
//
#include <hip/hip_runtime.h>
#include <math.h>

#define B 8
#define T 8192
#define D 512
#define M 512
#define POS 32
#define CHUNK 4
#define NCHUNK (T / CHUNK)     // 2048 fine chunks per batch
#define GRP 32                 // fine chunks per coarse group
#define NGRP (NCHUNK / GRP)    // 64 groups per batch
#define BM (B * M)             // 4096
#define KD 512                 // GEMM K (fourier part hoisted out)

typedef __attribute__((ext_vector_type(8))) short short8;
typedef __attribute__((ext_vector_type(4))) short short4v;
typedef __attribute__((ext_vector_type(4))) float floatx4;

static __device__ inline unsigned short f2bf(float f) {
    unsigned int u = __float_as_uint(f);
    unsigned int r = (u + 0x7fffu + ((u >> 16) & 1u)) >> 16;   // RNE
    return (unsigned short)r;
}
static __device__ inline float bf2f(unsigned short h) {
    return __uint_as_float(((unsigned int)h) << 16);
}

// ================= KA: fused {chunk-scan | wsplit | ffout} ==================
__global__ __launch_bounds__(256) void k_fusedA(const float* __restrict__ fe,
                                                const float* __restrict__ W,
                                                const float* __restrict__ bias,
                                                float* __restrict__ cp,
                                                float* __restrict__ gsum,
                                                short* __restrict__ WhT,
                                                short* __restrict__ WlT,
                                                float* __restrict__ ffout) {
    int blk = blockIdx.x;
    int tid = threadIdx.x;
    if (blk < 512) {
        // ---- chunk-scan: b = blk>>6, g = blk&63, 128 rows, full D (float2)
        int b = blk >> 6;
        int g = blk & 63;
        int d2 = tid << 1;
        const float* src = fe + ((size_t)(b * T + g * (GRP * CHUNK)) * D + d2);
        float* cpb = cp + ((size_t)b * NCHUNK + (size_t)g * GRP) * D + d2;
        float2 acc = {0.f, 0.f};
#pragma unroll 4
        for (int c = 0; c < GRP; ++c) {
#pragma unroll
            for (int r = 0; r < CHUNK; ++r) {
                float2 v = *(const float2*)(src + (size_t)(c * CHUNK + r) * D);
                acc.x += v.x; acc.y += v.y;
            }
            *(float2*)(cpb + (size_t)c * D) = acc;
        }
        *(float2*)(gsum + ((size_t)b * NGRP + g) * D + d2) = acc;
    } else if (blk < 640) {
        // ---- wsplit
        __shared__ float ws[32][65];
        int wb = blk - 512;
        int k0 = (wb & 15) * 32;
        int n0 = (wb >> 4) * 64;
        {
            int kk = tid >> 3;
            int nn = (tid & 7) << 3;
            const float* src = W + (size_t)(k0 + kk) * D + n0 + nn;
            float4 v0 = *(const float4*)src;
            float4 v1 = *(const float4*)(src + 4);
            ws[kk][nn + 0] = v0.x; ws[kk][nn + 1] = v0.y; ws[kk][nn + 2] = v0.z; ws[kk][nn + 3] = v0.w;
            ws[kk][nn + 4] = v1.x; ws[kk][nn + 5] = v1.y; ws[kk][nn + 6] = v1.z; ws[kk][nn + 7] = v1.w;
        }
        __syncthreads();
        int n = tid >> 2;
        int kq = (tid & 3) << 3;
        short8 hv, lv;
#pragma unroll
        for (int j = 0; j < 8; ++j) {
            float w = ws[kq + j][n];
            unsigned short hb = f2bf(w);
            hv[j] = (short)hb;
            lv[j] = (short)f2bf(w - bf2f(hb));
        }
        size_t off = (size_t)(n0 + n) * KD + k0 + kq;
        *(short8*)(WhT + off) = hv;
        *(short8*)(WlT + off) = lv;
    } else {
        // ---- ffout: 2 m per block
        int m = ((blk - 640) << 1) + (tid >> 7);
        int n4 = (tid & 127) << 2;
        float pos = (float)m * (1.0f / 511.0f);
        float4 acc = *(const float4*)(bias + n4);
#pragma unroll
        for (int j = 0; j < 16; ++j) {
            float freq = expf(0.46051701859880914f * (float)j);  // 1000^(j/15)
            float ang = pos * freq;
            float s = sinf(ang), c = cosf(ang);
            float4 wsn = *(const float4*)(W + (size_t)(D + j) * D + n4);
            float4 wcn = *(const float4*)(W + (size_t)(D + 16 + j) * D + n4);
            acc.x += s * wsn.x + c * wcn.x;
            acc.y += s * wsn.y + c * wcn.y;
            acc.z += s * wsn.z + c * wcn.z;
            acc.w += s * wsn.w + c * wcn.w;
        }
        *(float4*)(ffout + (size_t)m * D + n4) = acc;
    }
}

// ================= KB: exclusive scan of 64 coarse totals per batch =========
// grid = B*8 blocks (b x d-slice of 64), 64 threads, 1 float each.
__global__ __launch_bounds__(64) void k_scan_coarse(const float* __restrict__ gsum,
                                                    float* __restrict__ gx) {
    int b = blockIdx.x >> 3;
    int d = ((blockIdx.x & 7) << 6) + threadIdx.x;
    const float* gs = gsum + (size_t)b * NGRP * D + d;
    float* gxp = gx + (size_t)b * (NGRP + 1) * D + d;
    float acc = 0.f;
#pragma unroll
    for (int g = 0; g < NGRP; ++g) {
        gxp[(size_t)g * D] = acc;
        acc += gs[(size_t)g * D];
    }
    gxp[(size_t)NGRP * D] = acc;
}

// ================= KC: segment means -> Xh/Xl [4096][512] bf16 ==============
__global__ __launch_bounds__(128) void k_buildx(const float* __restrict__ fe,
                                                const int* __restrict__ bounds,
                                                const float* __restrict__ cp,
                                                const float* __restrict__ gx,
                                                short* __restrict__ Xh,
                                                short* __restrict__ Xl) {
    int bm = blockIdx.x;
    int b = bm / M;
    int b0 = bounds[bm * 2 + 0];
    int b1 = bounds[bm * 2 + 1];
    int s = min(max(b0, 0), T - 1);
    int e = max(min(b1, T), s + 1);
    int cs_ = s >> 2, ce = e >> 2;
    int d4 = threadIdx.x << 2;

    const float* cpb = cp + (size_t)b * NCHUNK * D;
    const float* gxb = gx + (size_t)b * (NGRP + 1) * D;

    float4 acc = *(const float4*)(gxb + (size_t)(ce >> 5) * D + d4);
    if (ce & 31) {
        float4 v = *(const float4*)(cpb + (size_t)(ce - 1) * D + d4);
        acc.x += v.x; acc.y += v.y; acc.z += v.z; acc.w += v.w;
    }
    {
        float4 p = *(const float4*)(gxb + (size_t)(cs_ >> 5) * D + d4);
        acc.x -= p.x; acc.y -= p.y; acc.z -= p.z; acc.w -= p.w;
        if (cs_ & 31) {
            float4 v = *(const float4*)(cpb + (size_t)(cs_ - 1) * D + d4);
            acc.x -= v.x; acc.y -= v.y; acc.z -= v.z; acc.w -= v.w;
        }
    }

    const float* feb = fe + (size_t)b * T * D + d4;
    for (int t = ce * CHUNK; t < e; ++t) {           // <= 3 iters
        float4 v = *(const float4*)(feb + (size_t)t * D);
        acc.x += v.x; acc.y += v.y; acc.z += v.z; acc.w += v.w;
    }
    for (int t = cs_ * CHUNK; t < s; ++t) {          // <= 3 iters
        float4 v = *(const float4*)(feb + (size_t)t * D);
        acc.x -= v.x; acc.y -= v.y; acc.z -= v.z; acc.w -= v.w;
    }
    float inv = 1.0f / (float)(e - s);
    float x0 = acc.x * inv, x1 = acc.y * inv, x2 = acc.z * inv, x3 = acc.w * inv;

    unsigned short h0 = f2bf(x0), h1 = f2bf(x1), h2 = f2bf(x2), h3 = f2bf(x3);
    short4v hv, lv;
    hv[0] = (short)h0; hv[1] = (short)h1; hv[2] = (short)h2; hv[3] = (short)h3;
    lv[0] = (short)f2bf(x0 - bf2f(h0));
    lv[1] = (short)f2bf(x1 - bf2f(h1));
    lv[2] = (short)f2bf(x2 - bf2f(h2));
    lv[3] = (short)f2bf(x3 - bf2f(h3));
    size_t off = (size_t)bm * KD + d4;
    *(short4v*)(Xh + off) = hv;
    *(short4v*)(Xl + off) = lv;
}

// ================= KD: MFMA GEMM, Out = (Xh+Xl)@(Wh+Wl) + ffout =============
// 64x64 block tile, 256 threads (2x2 waves of 32x32), K=512.
// BK=64 (two 32-k halves per barrier pair) + register prefetch of the next
// K-tile issued BEFORE the MFMA compute so global-load latency overlaps MFMAs.
#define BK 64
__global__ __launch_bounds__(256) void k_gemm(const short* __restrict__ Xh,
                                              const short* __restrict__ Xl,
                                              const short* __restrict__ WhT,
                                              const short* __restrict__ WlT,
                                              const float* __restrict__ ffout,
                                              float* __restrict__ out) {
    __shared__ short Ah[2][64 * 32], Al[2][64 * 32];
    __shared__ short Bh[2][64 * 32], Bl[2][64 * 32];     // 32 KB total
    int n0 = (blockIdx.x & 7) << 6;
    int m0 = (blockIdx.x >> 3) << 6;
    int tid = threadIdx.x;
    int w = tid >> 6;
    int l = tid & 63;
    int lm = l & 15;
    int q = l >> 4;
    int wm = (w & 1) << 5;
    int wn = (w >> 1) << 5;

    floatx4 acc[2][2];
#pragma unroll
    for (int i = 0; i < 2; ++i)
#pragma unroll
        for (int j = 0; j < 2; ++j)
            acc[i][j] = (floatx4){0.f, 0.f, 0.f, 0.f};

    int srow = tid >> 2;
    int skq = tid & 3;
    int sslot = skq ^ ((srow >> 1) & 3);
    int ldsoff = (srow << 5) + (sslot << 3);
    const short* gXh = Xh + (size_t)(m0 + srow) * KD + (skq << 3);
    const short* gXl = Xl + (size_t)(m0 + srow) * KD + (skq << 3);
    const short* gBh = WhT + (size_t)(n0 + srow) * KD + (skq << 3);
    const short* gBl = WlT + (size_t)(n0 + srow) * KD + (skq << 3);

    int aoff[2], boff[2];
#pragma unroll
    for (int mt = 0; mt < 2; ++mt) {
        int row = wm + (mt << 4) + lm;
        aoff[mt] = (row << 5) + ((q ^ ((row >> 1) & 3)) << 3);
    }
#pragma unroll
    for (int nt = 0; nt < 2; ++nt) {
        int row = wn + (nt << 4) + lm;
        boff[nt] = (row << 5) + ((q ^ ((row >> 1) & 3)) << 3);
    }

    // prologue prefetch: K-tile 0 (both 32-k halves)
    short8 pxh[2], pxl[2], pbh[2], pbl[2];
#pragma unroll
    for (int h = 0; h < 2; ++h) {
        pxh[h] = *(const short8*)(gXh + (h << 5));
        pxl[h] = *(const short8*)(gXl + (h << 5));
        pbh[h] = *(const short8*)(gBh + (h << 5));
        pbl[h] = *(const short8*)(gBl + (h << 5));
    }

    for (int k0 = 0; k0 < KD; k0 += BK) {   // 8 iterations
        __syncthreads();
#pragma unroll
        for (int h = 0; h < 2; ++h) {
            *(short8*)(&Ah[h][ldsoff]) = pxh[h];
            *(short8*)(&Al[h][ldsoff]) = pxl[h];
            *(short8*)(&Bh[h][ldsoff]) = pbh[h];
            *(short8*)(&Bl[h][ldsoff]) = pbl[h];
        }
        __syncthreads();

        // prefetch next K-tile while computing this one
        int kn = k0 + BK;
        if (kn < KD) {
#pragma unroll
            for (int h = 0; h < 2; ++h) {
                pxh[h] = *(const short8*)(gXh + kn + (h << 5));
                pxl[h] = *(const short8*)(gXl + kn + (h << 5));
                pbh[h] = *(const short8*)(gBh + kn + (h << 5));
                pbl[h] = *(const short8*)(gBl + kn + (h << 5));
            }
        }

#pragma unroll
        for (int h = 0; h < 2; ++h) {
            short8 ah[2], al[2], bh[2], bl[2];
#pragma unroll
            for (int mt = 0; mt < 2; ++mt) {
                ah[mt] = *(const short8*)(&Ah[h][aoff[mt]]);
                al[mt] = *(const short8*)(&Al[h][aoff[mt]]);
            }
#pragma unroll
            for (int nt = 0; nt < 2; ++nt) {
                bh[nt] = *(const short8*)(&Bh[h][boff[nt]]);
                bl[nt] = *(const short8*)(&Bl[h][boff[nt]]);
            }
#pragma unroll
            for (int mt = 0; mt < 2; ++mt)
#pragma unroll
                for (int nt = 0; nt < 2; ++nt) {
                    acc[mt][nt] = __builtin_amdgcn_mfma_f32_16x16x32_bf16(
                        ah[mt], bh[nt], acc[mt][nt], 0, 0, 0);
                    acc[mt][nt] = __builtin_amdgcn_mfma_f32_16x16x32_bf16(
                        ah[mt], bl[nt], acc[mt][nt], 0, 0, 0);
                    acc[mt][nt] = __builtin_amdgcn_mfma_f32_16x16x32_bf16(
                        al[mt], bh[nt], acc[mt][nt], 0, 0, 0);
                }
        }
    }

#pragma unroll
    for (int mt = 0; mt < 2; ++mt) {
#pragma unroll
        for (int nt = 0; nt < 2; ++nt) {
            int gcol = n0 + wn + (nt << 4) + lm;
#pragma unroll
            for (int r = 0; r < 4; ++r) {
                int grow = m0 + wm + (mt << 4) + (q << 2) + r;
                float f = ffout[(size_t)(grow & (M - 1)) * D + gcol];
                out[(size_t)grow * D + gcol] = acc[mt][nt][r] + f;
            }
        }
    }
}

extern "C" void kernel_launch(void* const* d_in, const int* in_sizes, int n_in,
                              void* d_out, int out_size, void* d_ws, size_t ws_size,
                              hipStream_t stream) {
    const float* fe = (const float*)d_in[0];
    const int* bounds = (const int*)d_in[1];
    const float* W = (const float*)d_in[2];
    const float* bias = (const float*)d_in[3];
    float* out = (float*)d_out;

    float* cp = (float*)d_ws;                                  // 8*2048*512 f32 = 33.5 MB
    float* gsum = cp + (size_t)B * NCHUNK * D;                 // 1 MB
    float* gx = gsum + (size_t)B * NGRP * D;                   // 1.06 MB
    float* ffout = gx + (size_t)B * (NGRP + 1) * D;            // 1 MB
    short* Xh = (short*)(ffout + (size_t)M * D);               // 4 MB
    short* Xl = Xh + (size_t)BM * KD;                          // 4 MB
    short* WhT = Xl + (size_t)BM * KD;                         // 0.5 MB
    short* WlT = WhT + (size_t)KD * D;                         // 0.5 MB

    k_fusedA<<<896, 256, 0, stream>>>(fe, W, bias, cp, gsum, WhT, WlT, ffout);
    k_scan_coarse<<<B * 8, 64, 0, stream>>>(gsum, gx);
    k_buildx<<<BM, 128, 0, stream>>>(fe, bounds, cp, gx, Xh, Xl);
    k_gemm<<<64 * 8, 256, 0, stream>>>(Xh, Xl, WhT, WlT, ffout, out);
}